// Round 2
// baseline (111.182 us; speedup 1.0000x reference)
//
#include <hip/hip_runtime.h>
#include <math.h>

// Exact IEEE semantics in the visibility path: no fma contraction anywhere.
#pragma clang fp contract(off)

#define IMG_H 128
#define IMG_W 128
#define HW (IMG_H * IMG_W)
#define NB 2
#define NV 1300
#define NF 2500
#define EPSF 1e-8f
#define NCHUNK 32
#define CHUNK ((NF + NCHUNK - 1) / NCHUNK) // 79
#define NREG 128                            // 8x16 grid of 16w x 8h px regions
#define NBLK (NREG * NB * NCHUNK)           // 8192

// ws layout (bytes):
//   vn     f32[NB*NV*3]          @ 0       (31200 B)
//   face   f4 [NB*NF*4]          @ 31232   (320000 B)
//   dbuf   u64[NB][HW]           @ 351488  (256 KB)   global depth|idx, atomicMin
#define OFF_FACE 31232
#define OFF_DBUF 351488

#define DINIT 0xFFFFFFFFFFFFFFFFull // memset 0xFF poison-safe init; > any real pk

__global__ __launch_bounds__(256) void k_face(const float* __restrict__ verts,
                                              const int* __restrict__ faces,
                                              float* __restrict__ vn,
                                              float4* __restrict__ face) {
    int i = blockIdx.x * 256 + threadIdx.x;
    if (i >= NB * NF) return;
    int b = i / NF;
    int f = i - b * NF;
    int i0 = faces[f * 3 + 0];
    int i1 = faces[f * 3 + 1];
    int i2 = faces[f * 3 + 2];
    const float* wv = verts + (size_t)b * NV * 3;
    // transform, bit-identical to ref: ndc = (12*(-vx))/(2-vz), z = 2-vz
    float v0x = wv[i0 * 3 + 0], v0y = wv[i0 * 3 + 1], v0z = wv[i0 * 3 + 2];
    float v1x = wv[i1 * 3 + 0], v1y = wv[i1 * 3 + 1], v1z = wv[i1 * 3 + 2];
    float v2x = wv[i2 * 3 + 0], v2y = wv[i2 * 3 + 1], v2z = wv[i2 * 3 + 2];
    float z0 = 2.0f - v0z, z1 = 2.0f - v1z, z2 = 2.0f - v2z;
    float p0x = (12.0f * (-v0x)) / z0, p0y = (12.0f * v0y) / z0;
    float p1x = (12.0f * (-v1x)) / z1, p1y = (12.0f * v1y) / z1;
    float p2x = (12.0f * (-v2x)) / z2, p2y = (12.0f * v2y) / z2;

    float t1 = (p1x - p0x) * (p2y - p0y);
    float t2 = (p1y - p0y) * (p2x - p0x);
    float area = t1 - t2;
    float aabs = fabsf(area);
    float area_safe = (aabs < EPSF) ? EPSF : area;
    bool valid = aabs > EPSF;
    float minx, maxx, miny, maxy;
    if (valid) {
        minx = fminf(p0x, fminf(p1x, p2x)) - 1e-3f;
        maxx = fmaxf(p0x, fmaxf(p1x, p2x)) + 1e-3f;
        miny = fminf(p0y, fminf(p1y, p2y)) - 1e-3f;
        maxy = fmaxf(p0y, fmaxf(p1y, p2y)) + 1e-3f;
    } else {
        minx = 1e30f; maxx = -1e30f; miny = 1e30f; maxy = -1e30f;
    }
    int o = (b * NF + f) * 4;
    face[o + 0] = make_float4(p2x - p1x, p2y - p1y, p1x, p1y);
    face[o + 1] = make_float4(p0x - p2x, p0y - p2y, p2x, p2y);
    face[o + 2] = make_float4(area_safe, z0, z1, z2);
    face[o + 3] = make_float4(minx, maxx, miny, maxy);

    // world-space face normal -> scatter to vertex normals
    float ax = v1x - v0x, ay = v1y - v0y, az = v1z - v0z;
    float bx = v2x - v0x, by = v2y - v0y, bz = v2z - v0z;
    float fnx = ay * bz - az * by;
    float fny = az * bx - ax * bz;
    float fnz = ax * by - ay * bx;
    float* vnb = vn + (size_t)b * NV * 3;
    atomicAdd(&vnb[i0 * 3 + 0], fnx);
    atomicAdd(&vnb[i0 * 3 + 1], fny);
    atomicAdd(&vnb[i0 * 3 + 2], fnz);
    atomicAdd(&vnb[i1 * 3 + 0], fnx);
    atomicAdd(&vnb[i1 * 3 + 1], fny);
    atomicAdd(&vnb[i1 * 3 + 2], fnz);
    atomicAdd(&vnb[i2 * 3 + 0], fnx);
    atomicAdd(&vnb[i2 * 3 + 1], fny);
    atomicAdd(&vnb[i2 * 3 + 2], fnz);
}

// Block = 128 threads = 2 waves over a 16w x 8h px region (each wave an 8x8
// tile). Phase 1: threads 0..CHUNK-1 test the chunk's face bboxes vs the
// region rect, then TILE TRIVIAL-REJECT: bound each affine edge function over
// each wave's 8x8 tile via corner products; if all corners are outside one
// edge (with margin DL >> FP rounding of the per-pixel edge expression), no
// pixel center in the tile can pass the exact test -> drop from that wave's
// list. Conservative only; per-pixel exact path unchanged (bit-exact).
// Phase 2: each wave scans its own list; result merged via u64 atomicMin.
__global__ __launch_bounds__(128) void k_raster(const float4* __restrict__ face,
                                                unsigned long long* __restrict__ dbuf) {
    __shared__ float4 sface[CHUNK * 4];
    __shared__ int sidx[CHUNK];
    __shared__ unsigned short swl[2][CHUNK];
    __shared__ int sbase[2];
    __shared__ int sbaseA[2];
    __shared__ int sbaseB[2];

    int bx = blockIdx.x;
    int chunk = bx & (NCHUNK - 1);
    int tmp = bx >> 5;
    int b = tmp & 1;
    int reg = tmp >> 1;       // 0..127
    int r0 = (reg >> 3) * 8;  // 16 row-bands of 8 px
    int c0 = (reg & 7) * 16;  // 8 col-bands of 16 px
    int f0 = chunk * CHUNK;
    int nf = NF - f0; if (nf > CHUNK) nf = CHUNK;

    // px(c) = 1 - (2c+1)/128, strictly decreasing in c.
    float txmax   = 1.0f - (2.0f * (float)c0 + 1.0f) / 128.0f;        // px(c0):    tile A hi
    float txmid_h = 1.0f - (2.0f * (float)(c0 + 7) + 1.0f) / 128.0f;  // px(c0+7):  tile A lo
    float txmid_l = 1.0f - (2.0f * (float)(c0 + 8) + 1.0f) / 128.0f;  // px(c0+8):  tile B hi
    float txmin   = 1.0f - (2.0f * (float)(c0 + 15) + 1.0f) / 128.0f; // px(c0+15): tile B lo
    float tymax = 1.0f - (2.0f * (float)r0 + 1.0f) / 128.0f;
    float tymin = 1.0f - (2.0f * (float)(r0 + 7) + 1.0f) / 128.0f;

    const float4* fb = face + (size_t)b * NF * 4;
    int t = threadIdx.x;
    int wid = t >> 6, lid = t & 63;
    bool pass = false, pA = false, pB = false;
    float4 bb, E0, E1, FD;
    if (t < nf) {
        bb = fb[(f0 + t) * 4 + 3]; // {minx, maxx, miny, maxy}
        bool yok = (bb.w >= tymin) && (bb.z <= tymax);
        pA = yok && (bb.y >= txmid_h) && (bb.x <= txmax);   // overlaps tile A cols
        pB = yok && (bb.y >= txmin) && (bb.x <= txmid_l);   // overlaps tile B cols
        if (pA || pB) {
            E0 = fb[(f0 + t) * 4 + 0];
            E1 = fb[(f0 + t) * 4 + 1];
            FD = fb[(f0 + t) * 4 + 2];
            float as = FD.x;
            // edge e(x,y) = dx*(y-ay) - dy*(x-ax); bound over tile rectangles.
            // y-span terms (shared by both tiles):
            float u0l = E0.x * (tymin - E0.w), u0h = E0.x * (tymax - E0.w);
            float u0mn = fminf(u0l, u0h), u0mx = fmaxf(u0l, u0h);
            float u1l = E1.x * (tymin - E1.w), u1h = E1.x * (tymax - E1.w);
            float u1mn = fminf(u1l, u1h), u1mx = fmaxf(u1l, u1h);
            // x-span terms, tile A:
            float v0al = E0.y * (txmid_h - E0.z), v0ah = E0.y * (txmax - E0.z);
            float v0amn = fminf(v0al, v0ah), v0amx = fmaxf(v0al, v0ah);
            float v1al = E1.y * (txmid_h - E1.z), v1ah = E1.y * (txmax - E1.z);
            float v1amn = fminf(v1al, v1ah), v1amx = fmaxf(v1al, v1ah);
            // x-span terms, tile B:
            float v0bl = E0.y * (txmin - E0.z), v0bh = E0.y * (txmid_l - E0.z);
            float v0bmn = fminf(v0bl, v0bh), v0bmx = fmaxf(v0bl, v0bh);
            float v1bl = E1.y * (txmin - E1.z), v1bh = E1.y * (txmid_l - E1.z);
            float v1bmn = fminf(v1bl, v1bh), v1bmx = fmaxf(v1bl, v1bh);
            float e0amx = u0mx - v0amn, e0amn = u0mn - v0amx;
            float e1amx = u1mx - v1amn, e1amn = u1mn - v1amx;
            float e0bmx = u0mx - v0bmn, e0bmn = u0mn - v0bmx;
            float e1bmx = u1mx - v1bmn, e1bmn = u1mn - v1bmx;
            const float DL = 1e-4f; // >> max FP rounding of the edge exprs (~2e-7)
            bool okA, okB;
            if (as > 0.0f) {
                okA = (e0amx >= -DL) && (e1amx >= -DL) && (((as - e0amn) - e1amn) >= -DL);
                okB = (e0bmx >= -DL) && (e1bmx >= -DL) && (((as - e0bmn) - e1bmn) >= -DL);
            } else {
                okA = (e0amn <= DL) && (e1amn <= DL) && (((as - e0amx) - e1amx) <= DL);
                okB = (e0bmn <= DL) && (e1bmn <= DL) && (((as - e0bmx) - e1bmx) <= DL);
            }
            pA = pA && okA;
            pB = pB && okB;
        }
        pass = pA || pB;
    }
    unsigned long long m  = __ballot(pass);
    unsigned long long mA = __ballot(pA);
    unsigned long long mB = __ballot(pB);
    if (lid == 0) {
        sbase[wid]  = __popcll(m);
        sbaseA[wid] = __popcll(mA);
        sbaseB[wid] = __popcll(mB);
    }
    __syncthreads();
    if (pass) {
        unsigned long long lt = (1ull << lid) - 1ull;
        int pos = (wid ? sbase[0] : 0) + __popcll(m & lt);
        sface[pos * 4 + 0] = E0; // staged from registers (already loaded)
        sface[pos * 4 + 1] = E1;
        sface[pos * 4 + 2] = FD;
        sface[pos * 4 + 3] = bb;
        sidx[pos] = f0 + t;
        if (pA) swl[0][(wid ? sbaseA[0] : 0) + __popcll(mA & lt)] = (unsigned short)pos;
        if (pB) swl[1][(wid ? sbaseB[0] : 0) + __popcll(mB & lt)] = (unsigned short)pos;
    }
    __syncthreads();
    int cnt = wid ? (sbaseB[0] + sbaseB[1]) : (sbaseA[0] + sbaseA[1]);

    int r = r0 + (lid >> 3);
    int c = c0 + wid * 8 + (lid & 7);
    int p = r * IMG_W + c;
    float px = 1.0f - (2.0f * (float)c + 1.0f) / 128.0f;
    float py = 1.0f - (2.0f * (float)r + 1.0f) / 128.0f;

    unsigned long long best = DINIT;
    for (int j = 0; j < cnt; ++j) {
        int jj = swl[wid][j];
        float4 fbb = sface[jj * 4 + 3];
        if (px >= fbb.x && px <= fbb.y && py >= fbb.z && py <= fbb.w) {
            float4 e0v = sface[jj * 4 + 0];
            float4 e1v = sface[jj * 4 + 1];
            float4 fdv = sface[jj * 4 + 2];
            // exact ref order: e = (bx-ax)*(py-ay) - (by-ay)*(px-ax)
            float u1 = e0v.x * (py - e0v.w);
            float u2 = e0v.y * (px - e0v.z);
            float e0 = u1 - u2;
            float u3 = e1v.x * (py - e1v.w);
            float u4 = e1v.y * (px - e1v.z);
            float e1 = u3 - u4;
            float as = fdv.x;
            bool ok = (as > 0.0f) ? (e0 >= 0.0f && e1 >= 0.0f)
                                  : (e0 <= 0.0f && e1 <= 0.0f);
            if (ok) {
                float b0 = e0 / as; // true IEEE division, as in ref
                float b1 = e1 / as;
                float b2 = (1.0f - b0) - b1;
                if (b2 >= 0.0f) {
                    float S = ((b0 / fdv.y) + (b1 / fdv.z)) + (b2 / fdv.w);
                    if (S > EPSF) {
                        float depth = 1.0f / fmaxf(S, EPSF);
                        unsigned long long pk =
                            ((unsigned long long)__float_as_uint(depth) << 32) |
                            (unsigned)sidx[jj];
                        if (pk < best) best = pk;
                    }
                }
            }
        }
    }
    if (best != DINIT)
        atomicMin(&dbuf[(size_t)b * HW + p], best);
}

__global__ __launch_bounds__(256) void k_shade(const float* __restrict__ verts,
                                               const int* __restrict__ faces,
                                               const float* __restrict__ vn,
                                               const unsigned long long* __restrict__ dbuf,
                                               float* __restrict__ out) {
    int i = blockIdx.x * 256 + threadIdx.x; // 0..NB*HW-1
    int b = i >> 14;
    int p = i & (HW - 1);
    unsigned long long pk = dbuf[(size_t)b * HW + p];
    unsigned dbits = (unsigned)(pk >> 32);
    bool hit = dbits < 0x7F800000u;
    float cr = 255.0f, cg = 255.0f, cb = 255.0f, alpha = 0.0f;
    if (hit) {
        alpha = 1.0f;
        int f = (int)(unsigned)(pk & 0xFFFFFFFFull);
        int row = p >> 7;
        int col = p & 127;
        float px = 1.0f - (2.0f * (float)col + 1.0f) / 128.0f;
        float py = 1.0f - (2.0f * (float)row + 1.0f) / 128.0f;
        int i0 = faces[f * 3 + 0];
        int i1 = faces[f * 3 + 1];
        int i2 = faces[f * 3 + 2];
        const float* wv = verts + (size_t)b * NV * 3;
        float v0x = wv[i0 * 3 + 0], v0y = wv[i0 * 3 + 1], v0z = wv[i0 * 3 + 2];
        float v1x = wv[i1 * 3 + 0], v1y = wv[i1 * 3 + 1], v1z = wv[i1 * 3 + 2];
        float v2x = wv[i2 * 3 + 0], v2y = wv[i2 * 3 + 1], v2z = wv[i2 * 3 + 2];
        // transform, bit-identical to k_face/ref
        float z0 = 2.0f - v0z, z1 = 2.0f - v1z, z2 = 2.0f - v2z;
        float a0x = (12.0f * (-v0x)) / z0, a0y = (12.0f * v0y) / z0;
        float a1x = (12.0f * (-v1x)) / z1, a1y = (12.0f * v1y) / z1;
        float a2x = (12.0f * (-v2x)) / z2, a2y = (12.0f * v2y) / z2;

        float t1 = (a1x - a0x) * (a2y - a0y);
        float t2 = (a1y - a0y) * (a2x - a0x);
        float ar = t1 - t2;
        ar = (fabsf(ar) < EPSF) ? EPSF : ar;
        float u1 = (a2x - a1x) * (py - a1y);
        float u2 = (a2y - a1y) * (px - a1x);
        float bb0 = (u1 - u2) / ar;
        float u3 = (a0x - a2x) * (py - a2y);
        float u4 = (a0y - a2y) * (px - a2x);
        float bb1 = (u3 - u4) / ar;
        float bb2 = (1.0f - bb0) - bb1;
        float w0 = bb0 / z0;
        float w1 = bb1 / z1;
        float w2 = bb2 / z2;
        float denom = ((w0 + w1) + w2) + EPSF;
        float pc0 = w0 / denom;
        float pc1 = w1 / denom;
        float pc2 = w2 / denom;

        float posx = (pc0 * v0x + pc1 * v1x) + pc2 * v2x;
        float posy = (pc0 * v0y + pc1 * v1y) + pc2 * v2y;
        float posz = (pc0 * v0z + pc1 * v1z) + pc2 * v2z;

        const float* vnb = vn + (size_t)b * NV * 3;
        float n0x = vnb[i0 * 3 + 0], n0y = vnb[i0 * 3 + 1], n0z = vnb[i0 * 3 + 2];
        float n1x = vnb[i1 * 3 + 0], n1y = vnb[i1 * 3 + 1], n1z = vnb[i1 * 3 + 2];
        float n2x = vnb[i2 * 3 + 0], n2y = vnb[i2 * 3 + 1], n2z = vnb[i2 * 3 + 2];
        float in0 = 1.0f / (sqrtf(n0x * n0x + n0y * n0y + n0z * n0z) + EPSF);
        float in1 = 1.0f / (sqrtf(n1x * n1x + n1y * n1y + n1z * n1z) + EPSF);
        float in2 = 1.0f / (sqrtf(n2x * n2x + n2y * n2y + n2z * n2z) + EPSF);
        n0x *= in0; n0y *= in0; n0z *= in0;
        n1x *= in1; n1y *= in1; n1z *= in1;
        n2x *= in2; n2y *= in2; n2z *= in2;
        float nx = (pc0 * n0x + pc1 * n1x) + pc2 * n2x;
        float ny = (pc0 * n0y + pc1 * n1y) + pc2 * n2y;
        float nz = (pc0 * n0z + pc1 * n1z) + pc2 * n2z;
        float inn = 1.0f / (sqrtf(nx * nx + ny * ny + nz * nz) + EPSF);
        nx *= inn; ny *= inn; nz *= inn;

        float lx = 0.0f - posx, ly = 1.0f - posy, lz = 3.0f - posz;
        float iln = 1.0f / (sqrtf(lx * lx + ly * ly + lz * lz) + EPSF);
        lx *= iln; ly *= iln; lz *= iln;
        float vx = 0.0f - posx, vy = 0.0f - posy, vz = 2.0f - posz;
        float ivn = 1.0f / (sqrtf(vx * vx + vy * vy + vz * vz) + EPSF);
        vx *= ivn; vy *= ivn; vz *= ivn;

        float ndl = nx * lx + ny * ly + nz * lz;
        float ndlr = fmaxf(ndl, 0.0f);
        float rx = 2.0f * ndl * nx - lx;
        float ry = 2.0f * ndl * ny - ly;
        float rz = 2.0f * ndl * nz - lz;
        float sc = fmaxf(rx * vx + ry * vy + rz * vz, 0.0f);
        float spec = 0.2f * 0.6f * powf(sc, 10.0f);
        float shade = 0.5f * 1.0f + 0.3f * 1.0f * ndlr;
        cr = ((142.0f / 255.0f) * shade + spec) * 255.0f;
        cg = ((179.0f / 255.0f) * shade + spec) * 255.0f;
        cb = ((247.0f / 255.0f) * shade + spec) * 255.0f;
    }
    float* img = out + (size_t)b * 3 * HW;
    img[0 * HW + p] = cr;
    img[1 * HW + p] = cg;
    img[2 * HW + p] = cb;
    out[(size_t)NB * 3 * HW + (size_t)b * HW + p] = alpha;
}

extern "C" void kernel_launch(void* const* d_in, const int* in_sizes, int n_in,
                              void* d_out, int out_size, void* d_ws, size_t ws_size,
                              hipStream_t stream) {
    const float* verts = (const float*)d_in[0]; // [NB, NV, 3]
    const int* faces = (const int*)d_in[1];     // [NF, 3]
    char* ws = (char*)d_ws;
    float* vn = (float*)(ws + 0);
    float4* face = (float4*)(ws + OFF_FACE);
    unsigned long long* dbuf = (unsigned long long*)(ws + OFF_DBUF);
    float* out = (float*)d_out;

    hipMemsetAsync(vn, 0, NB * NV * 3 * sizeof(float), stream);
    hipMemsetAsync(dbuf, 0xFF, (size_t)NB * HW * sizeof(unsigned long long), stream);
    k_face<<<(NB * NF + 255) / 256, 256, 0, stream>>>(verts, faces, vn, face);
    k_raster<<<NBLK, 128, 0, stream>>>(face, dbuf);
    k_shade<<<(NB * HW) / 256, 256, 0, stream>>>(verts, faces, vn, dbuf, out);
}

// Round 3
// 101.761 us; speedup vs baseline: 1.0926x; 1.0926x over previous
//
#include <hip/hip_runtime.h>
#include <math.h>

// Exact IEEE semantics in the visibility path: no fma contraction anywhere.
#pragma clang fp contract(off)

#define IMG_H 128
#define IMG_W 128
#define HW (IMG_H * IMG_W)
#define NB 2
#define NV 1300
#define NF 2500
#define EPSF 1e-8f
#define NCHUNK 32
#define CHUNK ((NF + NCHUNK - 1) / NCHUNK) // 79
#define NREG 128                            // 8x16 grid of 16w x 8h px regions
#define NBLK (NREG * NB * NCHUNK)           // 8192

// ws layout (bytes):
//   vn     f32[NB*NV*3]          @ 0       (31200 B)
//   face   f4 [NB*NF*4]          @ 31232   (320000 B)
//   dbuf   u64[NCHUNK][NB][HW]   @ 351488  (8 MB)     per-chunk depth|idx slab
#define OFF_FACE 31232
#define OFF_DBUF 351488

#define DINIT 0x7F800000FFFFFFFFull // depth=+inf, fidx=~0

__global__ __launch_bounds__(256) void k_face(const float* __restrict__ verts,
                                              const int* __restrict__ faces,
                                              float* __restrict__ vn,
                                              float4* __restrict__ face) {
    int i = blockIdx.x * 256 + threadIdx.x;
    if (i >= NB * NF) return;
    int b = i / NF;
    int f = i - b * NF;
    int i0 = faces[f * 3 + 0];
    int i1 = faces[f * 3 + 1];
    int i2 = faces[f * 3 + 2];
    const float* wv = verts + (size_t)b * NV * 3;
    // transform, bit-identical to ref: ndc = (12*(-vx))/(2-vz), z = 2-vz
    float v0x = wv[i0 * 3 + 0], v0y = wv[i0 * 3 + 1], v0z = wv[i0 * 3 + 2];
    float v1x = wv[i1 * 3 + 0], v1y = wv[i1 * 3 + 1], v1z = wv[i1 * 3 + 2];
    float v2x = wv[i2 * 3 + 0], v2y = wv[i2 * 3 + 1], v2z = wv[i2 * 3 + 2];
    float z0 = 2.0f - v0z, z1 = 2.0f - v1z, z2 = 2.0f - v2z;
    float p0x = (12.0f * (-v0x)) / z0, p0y = (12.0f * v0y) / z0;
    float p1x = (12.0f * (-v1x)) / z1, p1y = (12.0f * v1y) / z1;
    float p2x = (12.0f * (-v2x)) / z2, p2y = (12.0f * v2y) / z2;

    float t1 = (p1x - p0x) * (p2y - p0y);
    float t2 = (p1y - p0y) * (p2x - p0x);
    float area = t1 - t2;
    float aabs = fabsf(area);
    float area_safe = (aabs < EPSF) ? EPSF : area;
    bool valid = aabs > EPSF;
    float minx, maxx, miny, maxy;
    if (valid) {
        minx = fminf(p0x, fminf(p1x, p2x)) - 1e-3f;
        maxx = fmaxf(p0x, fmaxf(p1x, p2x)) + 1e-3f;
        miny = fminf(p0y, fminf(p1y, p2y)) - 1e-3f;
        maxy = fmaxf(p0y, fmaxf(p1y, p2y)) + 1e-3f;
    } else {
        minx = 1e30f; maxx = -1e30f; miny = 1e30f; maxy = -1e30f;
    }
    int o = (b * NF + f) * 4;
    face[o + 0] = make_float4(p2x - p1x, p2y - p1y, p1x, p1y);
    face[o + 1] = make_float4(p0x - p2x, p0y - p2y, p2x, p2y);
    face[o + 2] = make_float4(area_safe, z0, z1, z2);
    face[o + 3] = make_float4(minx, maxx, miny, maxy);

    // world-space face normal -> scatter to vertex normals
    float ax = v1x - v0x, ay = v1y - v0y, az = v1z - v0z;
    float bx = v2x - v0x, by = v2y - v0y, bz = v2z - v0z;
    float fnx = ay * bz - az * by;
    float fny = az * bx - ax * bz;
    float fnz = ax * by - ay * bx;
    float* vnb = vn + (size_t)b * NV * 3;
    atomicAdd(&vnb[i0 * 3 + 0], fnx);
    atomicAdd(&vnb[i0 * 3 + 1], fny);
    atomicAdd(&vnb[i0 * 3 + 2], fnz);
    atomicAdd(&vnb[i1 * 3 + 0], fnx);
    atomicAdd(&vnb[i1 * 3 + 1], fny);
    atomicAdd(&vnb[i1 * 3 + 2], fnz);
    atomicAdd(&vnb[i2 * 3 + 0], fnx);
    atomicAdd(&vnb[i2 * 3 + 1], fny);
    atomicAdd(&vnb[i2 * 3 + 2], fnz);
}

// Block = 128 threads = 2 fully INDEPENDENT waves (zero __syncthreads).
// Each wave owns an 8x8 px tile and: (1) tests all <=79 faces of its chunk
// against its tile (bbox + conservative edge-corner cull), compacting
// survivors into a per-wave LDS segment (staged from registers); (2) scans
// its own list with the bit-exact per-pixel path; (3) one coalesced store
// into the per-chunk depth slab. No barriers, no atomics, no cross-wave LDS.
__global__ __launch_bounds__(128) void k_raster(const float4* __restrict__ face,
                                                unsigned long long* __restrict__ dbuf) {
    __shared__ float4 sface[2][CHUNK * 4];
    __shared__ unsigned short sidx[2][CHUNK];

    int bx = blockIdx.x;
    int chunk = bx & (NCHUNK - 1);
    int tmp = bx >> 5;
    int b = tmp & 1;
    int reg = tmp >> 1;       // 0..127
    int r0 = (reg >> 3) * 8;  // 16 row-bands of 8 px
    int c0 = (reg & 7) * 16;  // 8 col-bands of 16 px
    int f0 = chunk * CHUNK;
    int nf = NF - f0; if (nf > CHUNK) nf = CHUNK;

    int t = threadIdx.x;
    int wid = t >> 6, lid = t & 63;
    int cw0 = c0 + wid * 8;

    // px(c) = 1 - (2c+1)/128, strictly decreasing in c; tile pixel-center box.
    float txhi = 1.0f - (2.0f * (float)cw0 + 1.0f) / 128.0f;
    float txlo = 1.0f - (2.0f * (float)(cw0 + 7) + 1.0f) / 128.0f;
    float tyhi = 1.0f - (2.0f * (float)r0 + 1.0f) / 128.0f;
    float tylo = 1.0f - (2.0f * (float)(r0 + 7) + 1.0f) / 128.0f;

    const float4* fb = face + (size_t)b * NF * 4;

    int cnt = 0;
    for (int base = 0; base < nf; base += 64) {
        int tt = base + lid;
        bool pass = false;
        float4 bb, E0, E1, FD;
        if (tt < nf) {
            bb = fb[(f0 + tt) * 4 + 3]; // {minx, maxx, miny, maxy}
            pass = (bb.y >= txlo) && (bb.x <= txhi) && (bb.w >= tylo) && (bb.z <= tyhi);
            if (pass) {
                E0 = fb[(f0 + tt) * 4 + 0];
                E1 = fb[(f0 + tt) * 4 + 1];
                FD = fb[(f0 + tt) * 4 + 2];
                float as = FD.x;
                // Bound each affine edge fn over the tile rect via corner
                // products; all-corners-outside (with DL >> FP rounding of
                // the per-pixel edge expr ~2e-7) => no pixel center passes.
                float u0l = E0.x * (tylo - E0.w), u0h = E0.x * (tyhi - E0.w);
                float u0mn = fminf(u0l, u0h), u0mx = fmaxf(u0l, u0h);
                float u1l = E1.x * (tylo - E1.w), u1h = E1.x * (tyhi - E1.w);
                float u1mn = fminf(u1l, u1h), u1mx = fmaxf(u1l, u1h);
                float v0l = E0.y * (txlo - E0.z), v0h = E0.y * (txhi - E0.z);
                float v0mn = fminf(v0l, v0h), v0mx = fmaxf(v0l, v0h);
                float v1l = E1.y * (txlo - E1.z), v1h = E1.y * (txhi - E1.z);
                float v1mn = fminf(v1l, v1h), v1mx = fmaxf(v1l, v1h);
                float e0mx = u0mx - v0mn, e0mn = u0mn - v0mx;
                float e1mx = u1mx - v1mn, e1mn = u1mn - v1mx;
                const float DL = 1e-4f;
                bool ok;
                if (as > 0.0f) {
                    ok = (e0mx >= -DL) && (e1mx >= -DL) && (((as - e0mn) - e1mn) >= -DL);
                } else {
                    ok = (e0mn <= DL) && (e1mn <= DL) && (((as - e0mx) - e1mx) <= DL);
                }
                pass = ok;
            }
        }
        unsigned long long m = __ballot(pass);
        if (pass) {
            int pos = cnt + __popcll(m & ((1ull << lid) - 1ull));
            sface[wid][pos * 4 + 0] = E0; // staged from registers
            sface[wid][pos * 4 + 1] = E1;
            sface[wid][pos * 4 + 2] = FD;
            sface[wid][pos * 4 + 3] = bb;
            sidx[wid][pos] = (unsigned short)tt;
        }
        cnt += __popcll(m);
    }

    int r = r0 + (lid >> 3);
    int c = cw0 + (lid & 7);
    int p = r * IMG_W + c;
    float px = 1.0f - (2.0f * (float)c + 1.0f) / 128.0f;
    float py = 1.0f - (2.0f * (float)r + 1.0f) / 128.0f;

    unsigned long long best = DINIT;
    for (int j = 0; j < cnt; ++j) {
        float4 fbb = sface[wid][j * 4 + 3]; // broadcast reads, conflict-free
        if (px >= fbb.x && px <= fbb.y && py >= fbb.z && py <= fbb.w) {
            float4 e0v = sface[wid][j * 4 + 0];
            float4 e1v = sface[wid][j * 4 + 1];
            float4 fdv = sface[wid][j * 4 + 2];
            // exact ref order: e = (bx-ax)*(py-ay) - (by-ay)*(px-ax)
            float u1 = e0v.x * (py - e0v.w);
            float u2 = e0v.y * (px - e0v.z);
            float e0 = u1 - u2;
            float u3 = e1v.x * (py - e1v.w);
            float u4 = e1v.y * (px - e1v.z);
            float e1 = u3 - u4;
            float as = fdv.x;
            bool ok = (as > 0.0f) ? (e0 >= 0.0f && e1 >= 0.0f)
                                  : (e0 <= 0.0f && e1 <= 0.0f);
            if (ok) {
                float b0 = e0 / as; // true IEEE division, as in ref
                float b1 = e1 / as;
                float b2 = (1.0f - b0) - b1;
                if (b2 >= 0.0f) {
                    float S = ((b0 / fdv.y) + (b1 / fdv.z)) + (b2 / fdv.w);
                    if (S > EPSF) {
                        float depth = 1.0f / fmaxf(S, EPSF);
                        unsigned long long pk =
                            ((unsigned long long)__float_as_uint(depth) << 32) |
                            (unsigned)(f0 + sidx[wid][j]);
                        if (pk < best) best = pk;
                    }
                }
            }
        }
    }
    dbuf[((size_t)chunk * NB + b) * HW + p] = best;
}

__global__ __launch_bounds__(64) void k_shade(const float* __restrict__ verts,
                                              const int* __restrict__ faces,
                                              const float* __restrict__ vn,
                                              const unsigned long long* __restrict__ dbuf,
                                              float* __restrict__ out) {
    int i = blockIdx.x * 64 + threadIdx.x; // 0..NB*HW-1
    int b = i >> 14;
    int p = i & (HW - 1);
    unsigned long long pk = DINIT;
    for (int k = 0; k < NCHUNK; ++k) {
        unsigned long long v = dbuf[((size_t)k * NB + b) * HW + p];
        if (v < pk) pk = v;
    }
    unsigned dbits = (unsigned)(pk >> 32);
    bool hit = dbits < 0x7F800000u;
    float cr = 255.0f, cg = 255.0f, cb = 255.0f, alpha = 0.0f;
    if (hit) {
        alpha = 1.0f;
        int f = (int)(unsigned)(pk & 0xFFFFFFFFull);
        int row = p >> 7;
        int col = p & 127;
        float px = 1.0f - (2.0f * (float)col + 1.0f) / 128.0f;
        float py = 1.0f - (2.0f * (float)row + 1.0f) / 128.0f;
        int i0 = faces[f * 3 + 0];
        int i1 = faces[f * 3 + 1];
        int i2 = faces[f * 3 + 2];
        const float* wv = verts + (size_t)b * NV * 3;
        float v0x = wv[i0 * 3 + 0], v0y = wv[i0 * 3 + 1], v0z = wv[i0 * 3 + 2];
        float v1x = wv[i1 * 3 + 0], v1y = wv[i1 * 3 + 1], v1z = wv[i1 * 3 + 2];
        float v2x = wv[i2 * 3 + 0], v2y = wv[i2 * 3 + 1], v2z = wv[i2 * 3 + 2];
        // transform, bit-identical to k_face/ref
        float z0 = 2.0f - v0z, z1 = 2.0f - v1z, z2 = 2.0f - v2z;
        float a0x = (12.0f * (-v0x)) / z0, a0y = (12.0f * v0y) / z0;
        float a1x = (12.0f * (-v1x)) / z1, a1y = (12.0f * v1y) / z1;
        float a2x = (12.0f * (-v2x)) / z2, a2y = (12.0f * v2y) / z2;

        float t1 = (a1x - a0x) * (a2y - a0y);
        float t2 = (a1y - a0y) * (a2x - a0x);
        float ar = t1 - t2;
        ar = (fabsf(ar) < EPSF) ? EPSF : ar;
        float u1 = (a2x - a1x) * (py - a1y);
        float u2 = (a2y - a1y) * (px - a1x);
        float bb0 = (u1 - u2) / ar;
        float u3 = (a0x - a2x) * (py - a2y);
        float u4 = (a0y - a2y) * (px - a2x);
        float bb1 = (u3 - u4) / ar;
        float bb2 = (1.0f - bb0) - bb1;
        float w0 = bb0 / z0;
        float w1 = bb1 / z1;
        float w2 = bb2 / z2;
        float denom = ((w0 + w1) + w2) + EPSF;
        float pc0 = w0 / denom;
        float pc1 = w1 / denom;
        float pc2 = w2 / denom;

        float posx = (pc0 * v0x + pc1 * v1x) + pc2 * v2x;
        float posy = (pc0 * v0y + pc1 * v1y) + pc2 * v2y;
        float posz = (pc0 * v0z + pc1 * v1z) + pc2 * v2z;

        const float* vnb = vn + (size_t)b * NV * 3;
        float n0x = vnb[i0 * 3 + 0], n0y = vnb[i0 * 3 + 1], n0z = vnb[i0 * 3 + 2];
        float n1x = vnb[i1 * 3 + 0], n1y = vnb[i1 * 3 + 1], n1z = vnb[i1 * 3 + 2];
        float n2x = vnb[i2 * 3 + 0], n2y = vnb[i2 * 3 + 1], n2z = vnb[i2 * 3 + 2];
        float in0 = 1.0f / (sqrtf(n0x * n0x + n0y * n0y + n0z * n0z) + EPSF);
        float in1 = 1.0f / (sqrtf(n1x * n1x + n1y * n1y + n1z * n1z) + EPSF);
        float in2 = 1.0f / (sqrtf(n2x * n2x + n2y * n2y + n2z * n2z) + EPSF);
        n0x *= in0; n0y *= in0; n0z *= in0;
        n1x *= in1; n1y *= in1; n1z *= in1;
        n2x *= in2; n2y *= in2; n2z *= in2;
        float nx = (pc0 * n0x + pc1 * n1x) + pc2 * n2x;
        float ny = (pc0 * n0y + pc1 * n1y) + pc2 * n2y;
        float nz = (pc0 * n0z + pc1 * n1z) + pc2 * n2z;
        float inn = 1.0f / (sqrtf(nx * nx + ny * ny + nz * nz) + EPSF);
        nx *= inn; ny *= inn; nz *= inn;

        float lx = 0.0f - posx, ly = 1.0f - posy, lz = 3.0f - posz;
        float iln = 1.0f / (sqrtf(lx * lx + ly * ly + lz * lz) + EPSF);
        lx *= iln; ly *= iln; lz *= iln;
        float vx = 0.0f - posx, vy = 0.0f - posy, vz = 2.0f - posz;
        float ivn = 1.0f / (sqrtf(vx * vx + vy * vy + vz * vz) + EPSF);
        vx *= ivn; vy *= ivn; vz *= ivn;

        float ndl = nx * lx + ny * ly + nz * lz;
        float ndlr = fmaxf(ndl, 0.0f);
        float rx = 2.0f * ndl * nx - lx;
        float ry = 2.0f * ndl * ny - ly;
        float rz = 2.0f * ndl * nz - lz;
        float sc = fmaxf(rx * vx + ry * vy + rz * vz, 0.0f);
        float spec = 0.2f * 0.6f * powf(sc, 10.0f);
        float shade = 0.5f * 1.0f + 0.3f * 1.0f * ndlr;
        cr = ((142.0f / 255.0f) * shade + spec) * 255.0f;
        cg = ((179.0f / 255.0f) * shade + spec) * 255.0f;
        cb = ((247.0f / 255.0f) * shade + spec) * 255.0f;
    }
    float* img = out + (size_t)b * 3 * HW;
    img[0 * HW + p] = cr;
    img[1 * HW + p] = cg;
    img[2 * HW + p] = cb;
    out[(size_t)NB * 3 * HW + (size_t)b * HW + p] = alpha;
}

extern "C" void kernel_launch(void* const* d_in, const int* in_sizes, int n_in,
                              void* d_out, int out_size, void* d_ws, size_t ws_size,
                              hipStream_t stream) {
    const float* verts = (const float*)d_in[0]; // [NB, NV, 3]
    const int* faces = (const int*)d_in[1];     // [NF, 3]
    char* ws = (char*)d_ws;
    float* vn = (float*)(ws + 0);
    float4* face = (float4*)(ws + OFF_FACE);
    unsigned long long* dbuf = (unsigned long long*)(ws + OFF_DBUF);
    float* out = (float*)d_out;

    hipMemsetAsync(vn, 0, NB * NV * 3 * sizeof(float), stream);
    k_face<<<(NB * NF + 255) / 256, 256, 0, stream>>>(verts, faces, vn, face);
    k_raster<<<NBLK, 128, 0, stream>>>(face, dbuf);
    k_shade<<<(NB * HW) / 64, 64, 0, stream>>>(verts, faces, vn, dbuf, out);
}